// Round 1
// baseline (212.821 us; speedup 1.0000x reference)
//
#include <hip/hip_runtime.h>
#include <math.h>

// Router: logits = x @ w^T (N=32768, C=1024, E=64), top-2 + softmax, stable
// k-major position-in-expert, capacity mask.
//
// R8 change vs R7:
// (1) router_main: depth-2 prefetch with counted vmcnt. K split into 16
//     chunks of 64 floats (16 KB), 4-buffer LDS ring in the same 64 KB.
//     Loop: issue chunk it+2 -> wait vmcnt(8) (oldest 4 = chunk it done)
//     -> s_barrier -> compute. 4 buffers is the MINIMUM safe ring: the
//     issue targets buf[(it+2)%4] while the slowest wave may still read
//     buf[(it-1)%4] computing it-1; (it+2)-(it-1)=3, and 3%4!=0 so they
//     never collide (3 buffers WOULD collide). Trailing wfrag L2 loads
//     only strengthen vmcnt(8) (chunk-it DMAs are strictly oldest).
//     DMA lead time goes from ~0.3us (compute only) to ~2 full
//     iterations -> HBM latency fully hidden.
// (2) rank_out: direct register-built float4 stores of the one-hot mask
//     (branchless compares) instead of zero-LDS/scatter/re-stream.

#define C_DIM 1024

typedef _Float16 f16x8 __attribute__((ext_vector_type(8)));
typedef float f32x16 __attribute__((ext_vector_type(16)));

// wf frag id q = s*4 + eh*2 + split; elem = q*512 + lane*8
// content: n = eh*32 + (lane&31) (expert), k = s*16 + (lane>>5)*8 + j
__global__ __launch_bounds__(256) void wprep(const float* __restrict__ w,
                                             _Float16* __restrict__ wf) {
    int id = blockIdx.x * 256 + threadIdx.x;   // 16384 frags-of-8
    int lane = id & 63;
    int q = id >> 6;            // 0..255
    int split = q & 1;
    int eh = (q >> 1) & 1;
    int s = q >> 2;             // 0..63
    int n = eh * 32 + (lane & 31);
    int k = s * 16 + (lane >> 5) * 8;
    const float* src = w + (size_t)n * C_DIM + k;
    f16x8 v;
    #pragma unroll
    for (int j = 0; j < 8; ++j) {
        float xv = src[j];
        _Float16 h = (_Float16)xv;
        v[j] = (split == 0) ? h : (_Float16)((xv - (float)h) * 2048.0f);
    }
    *(f16x8*)(wf + (size_t)id * 8) = v;
}

__global__ __launch_bounds__(256, 2) void router_main(
    const float* __restrict__ x, const _Float16* __restrict__ wf,
    int2* __restrict__ idx_ws, float2* __restrict__ probs_ws,
    int* __restrict__ hist)
{
    // xs: 4 buffers x 64 rows x 64 floats = 64 KB ring. Within a buffer,
    // a row has 16 16B-chunks; logical chunk c of row m lives at physical
    // chunk (c ^ (m&15)): ds_read_b128 conflict-free (bank-quad = pc&7,
    // row stride 256B == 0 mod 128B, identical conflict structure to the
    // verified R7 128-float-row layout) AND staging lane-contiguous
    // (global_load_lds writes wave-uniform base + lane*16B).
    __shared__ __align__(16) float xs[4 * 64 * 64];
    __shared__ int h2[128];

    const int tid  = threadIdx.x;
    const int lane = tid & 63;
    const int wv   = __builtin_amdgcn_readfirstlane(tid >> 6);
    const int th   = wv >> 1;      // token half
    const int eh   = wv & 1;       // expert half
    const int b    = blockIdx.x;
    const int m0   = b * 64;
    const int ph   = b & 15;       // K-phase stagger (16 chunks now)

    // staging map: 1024 16B chunks / 4 waves / 64 lanes = 4 instrs/thread
    uint32_t goff[4];
    #pragma unroll
    for (int i = 0; i < 4; ++i) {
        int p = wv * 256 + i * 64 + lane;  // physical chunk in buffer
        int m = p >> 4;                    // row 0..63
        int rem = p & 15;                  // physical chunk-in-row
        int c = rem ^ (m & 15);            // logical chunk
        goff[i] = (uint32_t)(m0 + m) * C_DIM + c * 4;  // float offset (+cn*64 later)
    }

    const int mm   = lane & 15;
    const int lh   = lane >> 5;
    const int mloc = th * 32 + (lane & 31);

    f32x16 ah, am;
    #pragma unroll
    for (int i = 0; i < 16; ++i) { ah[i] = 0.f; am[i] = 0.f; }

    const _Float16* wbase = wf + (size_t)eh * 1024 + (size_t)lane * 8;

    auto STAGE = [&](int cn, int bufi) {
        float* dst = xs + (size_t)bufi * 4096 + (size_t)(wv * 256) * 4;
        #pragma unroll
        for (int i = 0; i < 4; ++i)
            __builtin_amdgcn_global_load_lds(
                (const __attribute__((address_space(1))) uint32_t*)(x + goff[i] + cn * 64),
                (__attribute__((address_space(3))) uint32_t*)(dst + (size_t)(i * 64) * 4),
                16, 0, 0);
    };

    // prologue: chunks ph+0, ph+1 -> bufs 0,1 (8 DMAs/wave outstanding)
    STAGE(ph, 0);
    STAGE((ph + 1) & 15, 1);

    #pragma unroll 1
    for (int it = 0; it < 16; ++it) {
        const int cur = it & 3;
        if (it < 14) {
            // issue FIRST (depth-2), then wait for the oldest chunk only.
            STAGE((ph + it + 2) & 15, (it + 2) & 3);
            asm volatile("s_waitcnt vmcnt(8)\ns_barrier" ::: "memory");
        } else if (it == 14) {
            asm volatile("s_waitcnt vmcnt(4)\ns_barrier" ::: "memory");
        } else {
            asm volatile("s_waitcnt vmcnt(0)\ns_barrier" ::: "memory");
        }
        const int sb = ((ph + it) & 15) * 4;       // s-base of this chunk
        const float* xb = xs + (size_t)cur * 4096;
        #pragma unroll
        for (int s8 = 0; s8 < 4; ++s8) {
            const int s  = sb + s8;
            const int c0 = s8 * 4 + lh * 2;        // logical chunk 0..14
            const int pc0 = c0 ^ mm;
            const int pc1 = (c0 + 1) ^ mm;
            float4 a0 = *(const float4*)&xb[(size_t)(mloc * 16 + pc0) * 4];
            float4 a1 = *(const float4*)&xb[(size_t)(mloc * 16 + pc1) * 4];
            float av[8] = {a0.x, a0.y, a0.z, a0.w, a1.x, a1.y, a1.z, a1.w};
            f16x8 xh, xm;
            #pragma unroll
            for (int j = 0; j < 8; ++j) {
                _Float16 hh = (_Float16)av[j];
                xh[j] = hh;
                xm[j] = (_Float16)((av[j] - (float)hh) * 2048.0f);
            }
            const _Float16* wp = wbase + (size_t)s * 2048;
            f16x8 bh = *(const f16x8*)(wp);
            f16x8 bm = *(const f16x8*)(wp + 512);
            ah = __builtin_amdgcn_mfma_f32_32x32x16_f16(xh, bh, ah, 0, 0, 0);
            am = __builtin_amdgcn_mfma_f32_32x32x16_f16(xh, bm, am, 0, 0, 0);
            am = __builtin_amdgcn_mfma_f32_32x32x16_f16(xm, bh, am, 0, 0, 0);
        }
        // next iteration's barrier protects the ring (see header comment)
    }
    __syncthreads();   // xs dead; alias front of ring as part[64][69]

    {
        const float inv = 1.0f / 2048.0f;
        const int col = lane & 31;
        #pragma unroll
        for (int reg = 0; reg < 16; ++reg) {
            int row = (reg & 3) + 8 * (reg >> 2) + 4 * lh;
            xs[(size_t)(th * 32 + row) * 69 + eh * 32 + col] = ah[reg] + am[reg] * inv;
        }
    }
    if (tid < 128) h2[tid] = 0;
    __syncthreads();

    if (tid < 64) {
        float m1 = -3.0e38f, m2 = -3.0e38f;
        int   i1 = 0, i2 = 0;
        const float* row = xs + (size_t)tid * 69;
        for (int e = 0; e < 64; ++e) {
            float v = row[e];
            if (v > m1)      { m2 = m1; i2 = i1; m1 = v; i1 = e; }
            else if (v > m2) { m2 = v;  i2 = e; }
        }
        float e2 = expf(m2 - m1);
        float p1 = 1.f / (1.f + e2);
        int n = m0 + tid;
        probs_ws[n] = make_float2(p1, e2 * p1);
        idx_ws[n]   = make_int2(i1, i2);
        atomicAdd(&h2[i1], 1);
        atomicAdd(&h2[64 + i2], 1);
    }
    __syncthreads();
    if (tid < 128) hist[(size_t)b * 128 + tid] = h2[tid];
}

// exclusive prefix over groups for each of the 128 (k,expert) columns
__global__ __launch_bounds__(256) void scan_kernel(const int* __restrict__ hist,
                                                   int* __restrict__ offs,
                                                   int* __restrict__ tot, int G) {
    int c = blockIdx.x;          // 0..127
    int t = threadIdx.x;
    int ipt = G / 256;
    int base = t * ipt;
    int sum = 0;
    for (int j = 0; j < ipt; ++j) sum += hist[(size_t)(base + j) * 128 + c];
    int lane = t & 63, wvi = t >> 6;
    int sc = sum;
    #pragma unroll
    for (int d = 1; d < 64; d <<= 1) {
        int o = __shfl_up(sc, d, 64);
        if (lane >= d) sc += o;
    }
    __shared__ int wtot[4];
    if (lane == 63) wtot[wvi] = sc;
    __syncthreads();
    int pre = 0;
    for (int w2 = 0; w2 < wvi; ++w2) pre += wtot[w2];
    int run = pre + sc - sum;
    for (int j = 0; j < ipt; ++j) {
        int v = hist[(size_t)(base + j) * 128 + c];
        offs[(size_t)(base + j) * 128 + c] = run;
        run += v;
    }
    if (t == 255) tot[c] = run;
}

__global__ __launch_bounds__(256) void rank_out(
    const int2* __restrict__ idx_ws, const float2* __restrict__ probs_ws,
    const int* __restrict__ offs, const int* __restrict__ tot,
    float* __restrict__ out_mask, float* __restrict__ out_probs,
    float* __restrict__ out_idx,  float* __restrict__ out_rank, int cap)
{
    __shared__ int hot0[64], hot1[64];   // surviving one-hot columns, -1 if dropped
    const int g = blockIdx.x, t = threadIdx.x;

    if (t < 64) {
        const int l = t;
        const int n = g * 64 + l;
        int2   ii = idx_ws[n];
        float2 pp = probs_ws[n];
        int off0 = offs[g * 128 + ii.x];
        int off1 = offs[g * 128 + 64 + ii.y] + tot[ii.y];

        unsigned long long below = (1ull << l) - 1ull;
        unsigned long long mk0 = ~0ull, mk1 = ~0ull;
        #pragma unroll
        for (int bi = 0; bi < 6; ++bi) {
            unsigned long long b0 = __ballot((ii.x >> bi) & 1);
            unsigned long long b1 = __ballot((ii.y >> bi) & 1);
            mk0 &= ((ii.x >> bi) & 1) ? b0 : ~b0;
            mk1 &= ((ii.y >> bi) & 1) ? b1 : ~b1;
        }
        int rank0 = off0 + __popcll(mk0 & below);
        int rank1 = off1 + __popcll(mk1 & below);
        int c0 = rank0 < cap;
        int c1 = rank1 < cap;

        hot0[l] = c0 ? ii.x : -1;
        hot1[l] = c1 ? (64 + ii.y) : -1;

        out_probs[2 * n]     = c0 ? pp.x : 0.f;
        out_probs[2 * n + 1] = c1 ? pp.y : 0.f;
        out_idx[2 * n]       = (float)ii.x;
        out_idx[2 * n + 1]   = (float)ii.y;
        out_rank[2 * n]      = (float)rank0;
        out_rank[2 * n + 1]  = (float)rank1;
    }
    __syncthreads();

    // each thread owns a 32-float quarter of one token row; build the
    // one-hot float4s in registers (branchless) and stream them out.
    const int tok = t >> 2, q = t & 3;
    const int h0 = hot0[tok], h1 = hot1[tok];
    float* dst = out_mask + (size_t)g * 8192 + (size_t)tok * 128 + q * 32;
    #pragma unroll
    for (int j = 0; j < 8; ++j) {
        const int cb = q * 32 + j * 4;
        float4 v;
        v.x = (cb     == h0 || cb     == h1) ? 1.f : 0.f;
        v.y = (cb + 1 == h0 || cb + 1 == h1) ? 1.f : 0.f;
        v.z = (cb + 2 == h0 || cb + 2 == h1) ? 1.f : 0.f;
        v.w = (cb + 3 == h0 || cb + 3 == h1) ? 1.f : 0.f;
        *(float4*)(dst + j * 4) = v;
    }
}

extern "C" void kernel_launch(void* const* d_in, const int* in_sizes, int n_in,
                              void* d_out, int out_size, void* d_ws, size_t ws_size,
                              hipStream_t stream) {
    const float* x = (const float*)d_in[0];
    const float* w = (const float*)d_in[1];
    const int N = in_sizes[0] / C_DIM;    // 32768
    const int G = N / 64;                 // 512

    int cap = (int)floor(2.0 * 2.0 * (double)N / 64.0);
    cap += cap & 1;
    if (cap < 4) cap = 4;

    char* wsb = (char*)d_ws;
    _Float16* wfrag  = (_Float16*)wsb;    wsb += (size_t)131072 * 2;
    int2*   idx_ws   = (int2*)wsb;        wsb += (size_t)N * 8;
    float2* probs_ws = (float2*)wsb;      wsb += (size_t)N * 8;
    int*    hist     = (int*)wsb;         wsb += (size_t)G * 128 * 4;
    int*    offs     = (int*)wsb;         wsb += (size_t)G * 128 * 4;
    int*    tot      = (int*)wsb;

    float* out       = (float*)d_out;
    float* out_mask  = out;                          // N*2*64
    float* out_probs = out + (size_t)N * 128;        // N*2
    float* out_idx   = out_probs + (size_t)N * 2;    // N*2
    float* out_rank  = out_idx + (size_t)N * 2;      // N*2

    hipLaunchKernelGGL(wprep, dim3(64), dim3(256), 0, stream, w, wfrag);
    hipLaunchKernelGGL(router_main, dim3(G), dim3(256), 0, stream,
                       x, wfrag, idx_ws, probs_ws, hist);
    hipLaunchKernelGGL(scan_kernel, dim3(128), dim3(256), 0, stream,
                       hist, offs, tot, G);
    hipLaunchKernelGGL(rank_out, dim3(G), dim3(256), 0, stream,
                       idx_ws, probs_ws, offs, tot,
                       out_mask, out_probs, out_idx, out_rank, cap);
}